// Round 5
// baseline (233.167 us; speedup 1.0000x reference)
//
#include <hip/hip_runtime.h>
#include <math.h>

// Problem constants (fixed by the reference)
namespace {
constexpr int IN_DIMc = 159;   // L1*(DIM+1)+L2
constexpr int MDIMc   = 93;    // L2*DIM
constexpr int MATELc  = 2976;  // banded tril nnz
constexpr int ROWS    = MDIMc + MATELc;  // 3069
constexpr int SIGDIMc = 340;   // 4+16+64+256
constexpr int NCLSc   = 10;
}

// Device-global scratch for the [B, 3069] mean|cov intermediate.
// (static __device__ avoids any ws_size assumption; rows 3069..3071 unused)
__device__ float g_mc[256 * 3072];

// --------------------------------------------------------------------------
// Kernel 1: g_mc[b][r] = dot(x[b,:159], Wcat[r,:159]) + bcat[r]
// Tile: 64 rows x 32 batches per 256-thread block. W tile in LDS (b128
// per-lane reads, stride 164); x read via wave-uniform global loads
// (scalar path) - no x LDS tile.
// --------------------------------------------------------------------------
__global__ __launch_bounds__(256) void gemm_mc(
    const float* __restrict__ x, const float* __restrict__ Wm,
    const float* __restrict__ bm, const float* __restrict__ Wc,
    const float* __restrict__ bc)
{
  __shared__ __align__(16) float wls[64 * 164];  // [row][164], cols 159..163 = 0
  const int t  = threadIdx.x;
  const int r0 = blockIdx.x * 64;
  const int b0 = blockIdx.y * 32;

  for (int idx = t; idx < 64 * 164; idx += 256) {
    int rr = idx / 164, ii = idx - rr * 164;
    int r = r0 + rr;
    float v = 0.0f;
    if (ii < IN_DIMc) {
      if (r < MDIMc)      v = Wm[r * IN_DIMc + ii];
      else if (r < ROWS)  v = Wc[(r - MDIMc) * IN_DIMc + ii];
    }
    wls[idx] = v;
  }
  __syncthreads();

  const int rl = t & 63;    // row within tile
  const int bg = t >> 6;    // wave index = batch group (8 batches)
  const float* xr[8];
#pragma unroll
  for (int j = 0; j < 8; ++j) xr[j] = x + (b0 + bg * 8 + j) * IN_DIMc;

  float acc[8] = {0, 0, 0, 0, 0, 0, 0, 0};
  const float4* wls4 = (const float4*)wls;
  for (int c = 0; c < 39; ++c) {          // i = 0..155
    float4 wv = wls4[rl * 41 + c];
    const int i = c * 4;
#pragma unroll
    for (int j = 0; j < 8; ++j) {
      acc[j] = fmaf(wv.x, xr[j][i],     acc[j]);
      acc[j] = fmaf(wv.y, xr[j][i + 1], acc[j]);
      acc[j] = fmaf(wv.z, xr[j][i + 2], acc[j]);
      acc[j] = fmaf(wv.w, xr[j][i + 3], acc[j]);
    }
  }
  for (int i = 156; i < IN_DIMc; ++i) {   // epilogue (no x OOB read)
    float wv = wls[rl * 164 + i];
#pragma unroll
    for (int j = 0; j < 8; ++j) acc[j] = fmaf(wv, xr[j][i], acc[j]);
  }

  const int r = r0 + rl;
  if (r < ROWS) {
    float bias = (r < MDIMc) ? bm[r] : bc[r - MDIMc];
#pragma unroll
    for (int j = 0; j < 8; ++j)
      g_mc[(size_t)(b0 + bg * 8 + j) * ROWS + r] = acc[j] + bias;
  }
}

// --------------------------------------------------------------------------
// Kernel 2: one block (512 threads = 8 waves) per batch.
//  P0: stage x, mean, eps in LDS (cov read via uniform scalar loads in P1).
//  P1: newV[93][64] = banded-tril(cov) @ eps + mean.
//  P2: per wave, 8 paths: build increment buffer dx[62][4] once, then 62
//      Chen steps reading ONE broadcast ds_read_b128/step; dxa/dxb/dxc via
//      cndmask selects. Norm reduce; lambda: =1 if norm2<=4 (wave-uniform),
//      else exact 40-iter bisection (matches reference; Newton from mu=1
//      converges too slowly when the quartic term dominates - R4 failure).
//  P3: cross-wave reduce -> sig[340]; fused 340x10 linear + log_softmax.
// Lane layout: l = a*16+b*4+c. Lane holds S4[4l..4l+3], S3[l],
// S2[l>>2] (x4 replicated), S1[l>>4] (x16 replicated).
// --------------------------------------------------------------------------
__global__ __launch_bounds__(512) void path_sig(
    const float* __restrict__ x,
    const float* __restrict__ eps, const float* __restrict__ Wf,
    const float* __restrict__ bf, float* __restrict__ out)
{
  // LDS (floats). eps region [0,5952) is dead after P1; aliased by
  // dxbuf/part/sig/logits. Total 12253 floats = 49,012 B.
  constexpr int OFF_EPS  = 0;      // 5952  [93][64]
  constexpr int OFF_DX   = 0;      // alias: 8 waves * 63 * 4 = 2016
  constexpr int OFF_PART = 2016;   // alias: 8 * 340 = 2720
  constexpr int OFF_SIG  = 4736;   // alias: 340
  constexpr int OFF_LOG  = 5076;   // alias: 16
  constexpr int OFF_MEAN = 5952;   // 96
  constexpr int OFF_XS   = 6048;   // 160
  constexpr int OFF_NEWV = 6208;   // 93*65 = 6045 (stride 65)
  __shared__ __align__(16) float smem[12253];
  float* epsL  = smem + OFF_EPS;
  float* meanL = smem + OFF_MEAN;
  float* xsm   = smem + OFF_XS;
  float* newVL = smem + OFF_NEWV;

  const int t = threadIdx.x;
  const int b = blockIdx.x;

  // ---- P0: stage inputs ----
  for (int i = t; i < IN_DIMc; i += 512) xsm[i] = x[b * IN_DIMc + i];
  for (int i = t; i < MDIMc; i += 512) meanL[i] = g_mc[(size_t)b * ROWS + i];
  {
    const float4* ep4 = (const float4*)(eps + (size_t)b * MDIMc * 64);
    float4* el4 = (float4*)epsL;
    for (int i = t; i < MDIMc * 16; i += 512) el4[i] = ep4[i];
  }
  __syncthreads();

  // ---- P1: newV = M @ eps + mean; cov via wave-uniform global loads ----
  const int k  = t & 63;
  const int rg = t >> 6;
  {
    const float* covG = g_mc + (size_t)b * ROWS + MDIMc;
    for (int r = rg; r < MDIMc; r += 8) {
      const int X  = r / 3;
      const int tr = r - X * 3;
      float acc = meanL[r];
      const int tb = (tr * (tr + 1)) >> 1;
      for (int y = 0; y <= X; ++y) {
        const int i = X - y;                              // diagonal offset
        const int base = 6 * (31 * i - ((i * (i - 1)) >> 1)) + y * 6 + tb;
        for (int tc2 = 0; tc2 <= tr; ++tc2)
          acc = fmaf(covG[base + tc2], epsL[(y * 3 + tc2) * 64 + k], acc);
      }
      newVL[r * 65 + k] = acc;
    }
  }
  __syncthreads();

  // ---- P2: signatures ----
  const int w = rg;          // wave 0..7
  const int l = k;           // lane 0..63
  const int la = l >> 4, lb = (l >> 2) & 3, lc = l & 3;
  const bool aH = (la & 2) != 0, aL = (la & 1) != 0;
  const bool bH = (lb & 2) != 0, bL = (lb & 1) != 0;
  const bool cH = (lc & 2) != 0, cL = (lc & 1) != 0;
  float* dxb = smem + OFF_DX + w * 252;     // 63 float4 slots (62 + zero pad)
  float acc1 = 0.f, acc2 = 0.f, acc3 = 0.f;
  float4 acc4 = make_float4(0.f, 0.f, 0.f, 0.f);
  const float inv6 = 1.0f / 6.0f, inv24 = 1.0f / 24.0f;

#pragma unroll 1
  for (int j = 0; j < 8; ++j) {
    const int kk = w * 8 + j;
    // build increment buffer dx[i] = p[i+1]-p[i]; even i: old->new, odd: new->old
    if (l < 62) {
      const int m = l >> 1;
      float4 dv;
      if ((l & 1) == 0) {
        dv.x = newVL[(3 * m) * 65 + kk]     - xsm[3 * m];
        dv.y = newVL[(3 * m + 1) * 65 + kk] - xsm[3 * m + 1];
        dv.z = newVL[(3 * m + 2) * 65 + kk] - xsm[3 * m + 2];
        dv.w = xsm[128 + m] - xsm[96 + m];
      } else {
        dv.x = xsm[3 * m + 3] - newVL[(3 * m) * 65 + kk];
        dv.y = xsm[3 * m + 4] - newVL[(3 * m + 1) * 65 + kk];
        dv.z = xsm[3 * m + 5] - newVL[(3 * m + 2) * 65 + kk];
        dv.w = xsm[96 + m + 1] - xsm[128 + m];
      }
      *(float4*)(dxb + l * 4) = dv;
    } else if (l == 62) {
      *(float4*)(dxb + 62 * 4) = make_float4(0.f, 0.f, 0.f, 0.f);  // pad
    }
    __syncthreads();   // uniform across all 8 waves

    float s1a = 0.f, s2o = 0.f, s3 = 0.f;
    float4 s4 = make_float4(0.f, 0.f, 0.f, 0.f);
    float4 d = *(const float4*)dxb;
#pragma unroll 2
    for (int i = 0; i < 62; ++i) {
      float4 dn = *(const float4*)(dxb + (i + 1) * 4);   // prefetch (pad @62)
      float dxa = aH ? (aL ? d.w : d.z) : (aL ? d.y : d.x);
      float dxbv = bH ? (bL ? d.w : d.z) : (bL ? d.y : d.x);
      float dxc = cH ? (cL ? d.w : d.z) : (cL ? d.y : d.x);
      float bcv = dxbv * dxc;
      float i1 = fmaf(s1a, inv6, dxa * inv24);  // S1/6 + dxa/24
      float i2 = fmaf(s1a, 0.5f, dxa * inv6);   // S1/2 + dxa/6
      float u  = s2o * dxc;
      float cB = fmaf(u, 0.5f, s3);
      // T4[abcd] = S4 + dxd*(dxa*bc/24 + S1[a]*bc/6 + S2[ab]*dxc/2 + S3[abc])
      float coef = fmaf(i1, bcv, cB);
      s4.x = fmaf(coef, d.x, s4.x);
      s4.y = fmaf(coef, d.y, s4.y);
      s4.z = fmaf(coef, d.z, s4.z);
      s4.w = fmaf(coef, d.w, s4.w);
      // T3[abc] = S3 + dxa*bc/6 + S1[a]*bc/2 + S2[ab]*dxc
      s3 = fmaf(i2, bcv, u + s3);
      // T2[ab] = S2 + dxb*(dxa/2 + S1[a])
      s2o = fmaf(dxbv, fmaf(dxa, 0.5f, s1a), s2o);
      // T1[a] = S1 + dxa
      s1a += dxa;
      d = dn;
    }

    // ---- tensor normalization (Chevyrev-Oberhauser) ----
    float c4 = s4.x * s4.x + s4.y * s4.y + s4.z * s4.z + s4.w * s4.w;
    float c3v = s3 * s3;
    float c2v = (lc == 0) ? s2o * s2o : 0.f;          // count each S2 once
    float c1v = ((l & 15) == 0) ? s1a * s1a : 0.f;    // count each S1 once
#pragma unroll
    for (int off = 1; off < 64; off <<= 1) {
      c1v += __shfl_xor(c1v, off);
      c2v += __shfl_xor(c2v, off);
      c3v += __shfl_xor(c3v, off);
      c4  += __shfl_xor(c4, off);
    }
    float norm2 = 1.f + c1v + c2v + c3v + c4;
    float lam, lam2;
    if (norm2 <= 4.0f) {          // wave-uniform: phi(x)=x -> lam -> 1
      lam = 1.0f; lam2 = 1.0f;
    } else {
      // exact reference bisection (40 iters) on the quartic in m2 = lam^2.
      float psi = 8.0f - 16.0f / norm2;
      float lo = 0.f, hi = 1.f;
#pragma unroll 1
      for (int it = 0; it < 40; ++it) {
        float mid = 0.5f * (lo + hi);
        float m2 = mid * mid;
        float val =
            fmaf(m2, fmaf(m2, fmaf(m2, fmaf(m2, c4, c3v), c2v), c1v), 1.f);
        bool pos = val > psi;
        hi = pos ? mid : hi;
        lo = pos ? lo : mid;
      }
      lam = 0.5f * (lo + hi);
      lam2 = lam * lam;
    }
    const float lam3 = lam2 * lam, lam4 = lam2 * lam2;
    acc1 = fmaf(s1a, lam, acc1);
    acc2 = fmaf(s2o, lam2, acc2);
    acc3 = fmaf(s3, lam3, acc3);
    acc4.x = fmaf(s4.x, lam4, acc4.x);
    acc4.y = fmaf(s4.y, lam4, acc4.y);
    acc4.z = fmaf(s4.z, lam4, acc4.z);
    acc4.w = fmaf(s4.w, lam4, acc4.w);
  }

  // ---- P3: reduce over waves, final linear + log_softmax ----
  {
    float* part = smem + OFF_PART + w * SIGDIMc;
    if ((l & 15) == 0) part[l >> 4] = acc1;        // S1[0..3]
    if (lc == 0)       part[4 + (l >> 2)] = acc2;  // S2[0..15]
    part[20 + l] = acc3;                           // S3[0..63]
    *(float4*)(part + 84 + 4 * l) = acc4;          // S4[0..255]
  }
  __syncthreads();

  float* sig = smem + OFF_SIG;
  for (int jj = t; jj < SIGDIMc; jj += 512) {
    float s = 0.f;
#pragma unroll
    for (int ww = 0; ww < 8; ++ww) s += smem[OFF_PART + ww * SIGDIMc + jj];
    sig[jj] = s * (1.0f / 64.0f);                  // mean over K
  }
  __syncthreads();

  float* logits = smem + OFF_LOG;
  for (int c = w; c < NCLSc; c += 8) {
    float s = 0.f;
    for (int jj = l; jj < SIGDIMc; jj += 64)
      s = fmaf(sig[jj], Wf[c * SIGDIMc + jj], s);
#pragma unroll
    for (int off = 1; off < 64; off <<= 1) s += __shfl_xor(s, off);
    if (l == 0) logits[c] = s + bf[c];
  }
  __syncthreads();
  if (t < NCLSc) {
    float mx = logits[0];
#pragma unroll
    for (int i2 = 1; i2 < NCLSc; ++i2) mx = fmaxf(mx, logits[i2]);
    float se = 0.f;
#pragma unroll
    for (int i2 = 0; i2 < NCLSc; ++i2) se += expf(logits[i2] - mx);
    out[b * NCLSc + t] = logits[t] - mx - logf(se);
  }
}

extern "C" void kernel_launch(void* const* d_in, const int* in_sizes, int n_in,
                              void* d_out, int out_size, void* d_ws, size_t ws_size,
                              hipStream_t stream) {
  (void)in_sizes; (void)n_in; (void)out_size; (void)d_ws; (void)ws_size;
  const float* x   = (const float*)d_in[0];
  const float* Wm  = (const float*)d_in[1];
  const float* bm  = (const float*)d_in[2];
  const float* Wc  = (const float*)d_in[3];
  const float* bcv = (const float*)d_in[4];
  const float* Wf  = (const float*)d_in[5];
  const float* bf  = (const float*)d_in[6];
  const float* eps = (const float*)d_in[7];
  // d_in[8]/d_in[9] (x_idx/y_idx) are compile-time deterministic; hard-coded.
  float* out = (float*)d_out;

  gemm_mc<<<dim3(48, 8), 256, 0, stream>>>(x, Wm, bm, Wc, bcv);
  path_sig<<<dim3(256), 512, 0, stream>>>(x, eps, Wf, bf, out);
}

// Round 7
// 198.349 us; speedup vs baseline: 1.1755x; 1.1755x over previous
//
#include <hip/hip_runtime.h>
#include <math.h>

// Problem constants (fixed by the reference)
namespace {
constexpr int IN_DIMc = 159;   // L1*(DIM+1)+L2
constexpr int MDIMc   = 93;    // L2*DIM
constexpr int MATELc  = 2976;  // banded tril nnz
constexpr int ROWS    = MDIMc + MATELc;  // 3069
constexpr int SIGDIMc = 340;   // 4+16+64+256
constexpr int NCLSc   = 10;
}

// Device-global scratch for the [B, 3069] mean|cov intermediate.
// (static __device__ avoids any ws_size assumption; rows 3069..3071 unused)
__device__ float g_mc[256 * 3072];

// --------------------------------------------------------------------------
// Kernel 1: g_mc[b][r] = dot(x[b,:159], Wcat[r,:159]) + bcat[r]
// Tile: 64 rows x 32 batches per 256-thread block. W tile in LDS (b128
// per-lane reads, stride 164); x read via wave-uniform global loads
// (scalar path) - no x LDS tile.
// --------------------------------------------------------------------------
__global__ __launch_bounds__(256) void gemm_mc(
    const float* __restrict__ x, const float* __restrict__ Wm,
    const float* __restrict__ bm, const float* __restrict__ Wc,
    const float* __restrict__ bc)
{
  __shared__ __align__(16) float wls[64 * 164];  // [row][164], cols 159..163 = 0
  const int t  = threadIdx.x;
  const int r0 = blockIdx.x * 64;
  const int b0 = blockIdx.y * 32;

  for (int idx = t; idx < 64 * 164; idx += 256) {
    int rr = idx / 164, ii = idx - rr * 164;
    int r = r0 + rr;
    float v = 0.0f;
    if (ii < IN_DIMc) {
      if (r < MDIMc)      v = Wm[r * IN_DIMc + ii];
      else if (r < ROWS)  v = Wc[(r - MDIMc) * IN_DIMc + ii];
    }
    wls[idx] = v;
  }
  __syncthreads();

  const int rl = t & 63;    // row within tile
  const int bg = t >> 6;    // wave index = batch group (8 batches)
  const float* xr[8];
#pragma unroll
  for (int j = 0; j < 8; ++j) xr[j] = x + (b0 + bg * 8 + j) * IN_DIMc;

  float acc[8] = {0, 0, 0, 0, 0, 0, 0, 0};
  const float4* wls4 = (const float4*)wls;
  for (int c = 0; c < 39; ++c) {          // i = 0..155
    float4 wv = wls4[rl * 41 + c];
    const int i = c * 4;
#pragma unroll
    for (int j = 0; j < 8; ++j) {
      acc[j] = fmaf(wv.x, xr[j][i],     acc[j]);
      acc[j] = fmaf(wv.y, xr[j][i + 1], acc[j]);
      acc[j] = fmaf(wv.z, xr[j][i + 2], acc[j]);
      acc[j] = fmaf(wv.w, xr[j][i + 3], acc[j]);
    }
  }
  for (int i = 156; i < IN_DIMc; ++i) {   // epilogue (no x OOB read)
    float wv = wls[rl * 164 + i];
#pragma unroll
    for (int j = 0; j < 8; ++j) acc[j] = fmaf(wv, xr[j][i], acc[j]);
  }

  const int r = r0 + rl;
  if (r < ROWS) {
    float bias = (r < MDIMc) ? bm[r] : bc[r - MDIMc];
#pragma unroll
    for (int j = 0; j < 8; ++j)
      g_mc[(size_t)(b0 + bg * 8 + j) * ROWS + r] = acc[j] + bias;
  }
}

// --------------------------------------------------------------------------
// Kernel 2: one block (1024 threads = 16 waves) per batch.
//  P0: stage x, mean, eps in LDS (cov read via uniform scalar loads in P1).
//  P1: newV[93][64] = banded-tril(cov) @ eps + mean. One barrier after.
//  P2: BARRIER-FREE. Each wave handles 4 of the K=64 paths; dx buffer is
//      wave-private LDS (64 float4 slots -> depth-2 prefetch), so no block
//      sync is needed (same-wave LDS visibility via compiler lgkmcnt).
//      62 Chen steps/path: 1 broadcast ds_read_b128 + cndmask selects.
//      Norm shuffle-reduce; lambda via exact 40-iter bisection (norm2<=4
//      branch -> lam=1 is wave-uniform).
//  P3: one barrier; cross-wave reduce -> sig[340]; 340x10 linear + softmax.
// Lane layout: l = a*16+b*4+c. Lane holds S4[4l..4l+3], S3[l],
// S2[l>>2] (x4 replicated), S1[l>>4] (x16 replicated).
// --------------------------------------------------------------------------
__global__ __launch_bounds__(1024) void path_sig(
    const float* __restrict__ x,
    const float* __restrict__ eps, const float* __restrict__ Wf,
    const float* __restrict__ bf, float* __restrict__ out)
{
  // LDS (floats). eps region [0,5952) dead after P1 -> aliased by
  // part/sig/logits. dx region is separate (live during all of P2).
  // Total 16288 floats = 65,152 B (< 64 KiB static limit).
  constexpr int OFF_EPS  = 0;      // 5952  [93][64]
  constexpr int OFF_PART = 0;      // alias: 16 * 340 = 5440
  constexpr int OFF_SIG  = 5440;   // alias: 340
  constexpr int OFF_LOG  = 5780;   // alias: 16  (region ends 5796 < 5952)
  constexpr int OFF_MEAN = 5952;   // 96
  constexpr int OFF_XS   = 6048;   // 160
  constexpr int OFF_NEWV = 6208;   // 93*65 = 6045 (stride 65) -> ends 12253
  constexpr int OFF_DX   = 12256;  // 16 waves * 64 float4 = 4096 -> ends 16352
  __shared__ __align__(16) float smem[16352];
  float* epsL  = smem + OFF_EPS;
  float* meanL = smem + OFF_MEAN;
  float* xsm   = smem + OFF_XS;
  float* newVL = smem + OFF_NEWV;

  const int t = threadIdx.x;
  const int b = blockIdx.x;

  // ---- P0: stage inputs ----
  for (int i = t; i < IN_DIMc; i += 1024) xsm[i] = x[b * IN_DIMc + i];
  for (int i = t; i < MDIMc; i += 1024) meanL[i] = g_mc[(size_t)b * ROWS + i];
  {
    const float4* ep4 = (const float4*)(eps + (size_t)b * MDIMc * 64);
    float4* el4 = (float4*)epsL;
    for (int i = t; i < MDIMc * 16; i += 1024) el4[i] = ep4[i];
  }
  __syncthreads();

  // ---- P1: newV = M @ eps + mean; cov via wave-uniform global loads ----
  const int k  = t & 63;
  const int rg = t >> 6;          // wave id 0..15
  {
    const float* covG = g_mc + (size_t)b * ROWS + MDIMc;
    for (int r = rg; r < MDIMc; r += 16) {
      const int X  = r / 3;
      const int tr = r - X * 3;
      float acc = meanL[r];
      const int tb = (tr * (tr + 1)) >> 1;
      for (int y = 0; y <= X; ++y) {
        const int i = X - y;                              // diagonal offset
        const int base = 6 * (31 * i - ((i * (i - 1)) >> 1)) + y * 6 + tb;
        for (int tc2 = 0; tc2 <= tr; ++tc2)
          acc = fmaf(covG[base + tc2], epsL[(y * 3 + tc2) * 64 + k], acc);
      }
      newVL[r * 65 + k] = acc;
    }
  }
  __syncthreads();   // newV/xsm stable from here; no more barriers until P3

  // ---- P2: signatures (barrier-free; dx is wave-private LDS) ----
  const int w = rg;          // wave 0..15
  const int l = k;           // lane 0..63
  const int la = l >> 4, lb = (l >> 2) & 3, lc = l & 3;
  const bool aH = (la & 2) != 0, aL = (la & 1) != 0;
  const bool bH = (lb & 2) != 0, bL = (lb & 1) != 0;
  const bool cH = (lc & 2) != 0, cL = (lc & 1) != 0;
  float* dxb = smem + OFF_DX + w * 256;     // 64 float4 slots (62 + 2 pad)
  float acc1 = 0.f, acc2 = 0.f, acc3 = 0.f;
  float4 acc4 = make_float4(0.f, 0.f, 0.f, 0.f);
  const float inv6 = 1.0f / 6.0f, inv24 = 1.0f / 24.0f;

  if (l >= 62)  // zero the two prefetch-pad slots once (constant across paths)
    *(float4*)(dxb + l * 4) = make_float4(0.f, 0.f, 0.f, 0.f);

#pragma unroll 1
  for (int j = 0; j < 4; ++j) {
    const int kk = w * 4 + j;
    // build increment buffer dx[i] = p[i+1]-p[i]; even i: old->new, odd: new->old
    if (l < 62) {
      const int m = l >> 1;
      float4 dv;
      if ((l & 1) == 0) {
        dv.x = newVL[(3 * m) * 65 + kk]     - xsm[3 * m];
        dv.y = newVL[(3 * m + 1) * 65 + kk] - xsm[3 * m + 1];
        dv.z = newVL[(3 * m + 2) * 65 + kk] - xsm[3 * m + 2];
        dv.w = xsm[128 + m] - xsm[96 + m];
      } else {
        dv.x = xsm[3 * m + 3] - newVL[(3 * m) * 65 + kk];
        dv.y = xsm[3 * m + 4] - newVL[(3 * m + 1) * 65 + kk];
        dv.z = xsm[3 * m + 5] - newVL[(3 * m + 2) * 65 + kk];
        dv.w = xsm[96 + m + 1] - xsm[128 + m];
      }
      *(float4*)(dxb + l * 4) = dv;
    }
    // no __syncthreads: dxb is wave-private; compiler inserts lgkmcnt waits

    float s1a = 0.f, s2o = 0.f, s3 = 0.f;
    float4 s4 = make_float4(0.f, 0.f, 0.f, 0.f);
    const float4* dx4 = (const float4*)dxb;
    float4 d = dx4[0], dn = dx4[1];
#pragma unroll 2
    for (int i = 0; i < 62; ++i) {
      float4 d2 = dx4[i + 2];                  // depth-2 prefetch (pads @62,63)
      float dxa  = aH ? (aL ? d.w : d.z) : (aL ? d.y : d.x);
      float dxbv = bH ? (bL ? d.w : d.z) : (bL ? d.y : d.x);
      float dxc  = cH ? (cL ? d.w : d.z) : (cL ? d.y : d.x);
      float bcv = dxbv * dxc;
      float i1 = fmaf(s1a, inv6, dxa * inv24);  // S1/6 + dxa/24
      float i2 = fmaf(s1a, 0.5f, dxa * inv6);   // S1/2 + dxa/6
      float u  = s2o * dxc;
      float cB = fmaf(u, 0.5f, s3);
      // T4[abcd] = S4 + dxd*(dxa*bc/24 + S1[a]*bc/6 + S2[ab]*dxc/2 + S3[abc])
      float coef = fmaf(i1, bcv, cB);
      s4.x = fmaf(coef, d.x, s4.x);
      s4.y = fmaf(coef, d.y, s4.y);
      s4.z = fmaf(coef, d.z, s4.z);
      s4.w = fmaf(coef, d.w, s4.w);
      // T3[abc] = S3 + dxa*bc/6 + S1[a]*bc/2 + S2[ab]*dxc
      s3 = fmaf(i2, bcv, u + s3);
      // T2[ab] = S2 + dxb*(dxa/2 + S1[a])
      s2o = fmaf(dxbv, fmaf(dxa, 0.5f, s1a), s2o);
      // T1[a] = S1 + dxa
      s1a += dxa;
      d = dn; dn = d2;
    }

    // ---- tensor normalization (Chevyrev-Oberhauser) ----
    float c4 = s4.x * s4.x + s4.y * s4.y + s4.z * s4.z + s4.w * s4.w;
    float c3v = s3 * s3;
    float c2v = (lc == 0) ? s2o * s2o : 0.f;          // count each S2 once
    float c1v = ((l & 15) == 0) ? s1a * s1a : 0.f;    // count each S1 once
#pragma unroll
    for (int off = 1; off < 64; off <<= 1) {
      c1v += __shfl_xor(c1v, off);
      c2v += __shfl_xor(c2v, off);
      c3v += __shfl_xor(c3v, off);
      c4  += __shfl_xor(c4, off);
    }
    float norm2 = 1.f + c1v + c2v + c3v + c4;
    float lam, lam2;
    if (norm2 <= 4.0f) {          // wave-uniform: phi(x)=x -> lam -> 1
      lam = 1.0f; lam2 = 1.0f;
    } else {
      // exact reference bisection (40 iters) on the quartic in m2 = lam^2.
      float psi = 8.0f - 16.0f / norm2;
      float lo = 0.f, hi = 1.f;
#pragma unroll 1
      for (int it = 0; it < 40; ++it) {
        float mid = 0.5f * (lo + hi);
        float m2 = mid * mid;
        float val =
            fmaf(m2, fmaf(m2, fmaf(m2, fmaf(m2, c4, c3v), c2v), c1v), 1.f);
        bool pos = val > psi;
        hi = pos ? mid : hi;
        lo = pos ? lo : mid;
      }
      lam = 0.5f * (lo + hi);
      lam2 = lam * lam;
    }
    const float lam3 = lam2 * lam, lam4 = lam2 * lam2;
    acc1 = fmaf(s1a, lam, acc1);
    acc2 = fmaf(s2o, lam2, acc2);
    acc3 = fmaf(s3, lam3, acc3);
    acc4.x = fmaf(s4.x, lam4, acc4.x);
    acc4.y = fmaf(s4.y, lam4, acc4.y);
    acc4.z = fmaf(s4.z, lam4, acc4.z);
    acc4.w = fmaf(s4.w, lam4, acc4.w);
  }

  // ---- P3: reduce over waves, final linear + log_softmax ----
  {
    float* part = smem + OFF_PART + w * SIGDIMc;   // aliases dead eps region
    if ((l & 15) == 0) part[l >> 4] = acc1;        // S1[0..3]
    if (lc == 0)       part[4 + (l >> 2)] = acc2;  // S2[0..15]
    part[20 + l] = acc3;                           // S3[0..63]
    *(float4*)(part + 84 + 4 * l) = acc4;          // S4[0..255]
  }
  __syncthreads();

  float* sig = smem + OFF_SIG;
  for (int jj = t; jj < SIGDIMc; jj += 1024) {
    float s = 0.f;
#pragma unroll
    for (int ww = 0; ww < 16; ++ww) s += smem[OFF_PART + ww * SIGDIMc + jj];
    sig[jj] = s * (1.0f / 64.0f);                  // mean over K
  }
  __syncthreads();

  float* logits = smem + OFF_LOG;
  for (int c = w; c < NCLSc; c += 16) {
    float s = 0.f;
    for (int jj = l; jj < SIGDIMc; jj += 64)
      s = fmaf(sig[jj], Wf[c * SIGDIMc + jj], s);
#pragma unroll
    for (int off = 1; off < 64; off <<= 1) s += __shfl_xor(s, off);
    if (l == 0) logits[c] = s + bf[c];
  }
  __syncthreads();
  if (t < NCLSc) {
    float mx = logits[0];
#pragma unroll
    for (int i2 = 1; i2 < NCLSc; ++i2) mx = fmaxf(mx, logits[i2]);
    float se = 0.f;
#pragma unroll
    for (int i2 = 0; i2 < NCLSc; ++i2) se += expf(logits[i2] - mx);
    out[b * NCLSc + t] = logits[t] - mx - logf(se);
  }
}

extern "C" void kernel_launch(void* const* d_in, const int* in_sizes, int n_in,
                              void* d_out, int out_size, void* d_ws, size_t ws_size,
                              hipStream_t stream) {
  (void)in_sizes; (void)n_in; (void)out_size; (void)d_ws; (void)ws_size;
  const float* x   = (const float*)d_in[0];
  const float* Wm  = (const float*)d_in[1];
  const float* bm  = (const float*)d_in[2];
  const float* Wc  = (const float*)d_in[3];
  const float* bcv = (const float*)d_in[4];
  const float* Wf  = (const float*)d_in[5];
  const float* bf  = (const float*)d_in[6];
  const float* eps = (const float*)d_in[7];
  // d_in[8]/d_in[9] (x_idx/y_idx) are compile-time deterministic; hard-coded.
  float* out = (float*)d_out;

  gemm_mc<<<dim3(48, 8), 256, 0, stream>>>(x, Wm, bm, Wc, bcv);
  path_sig<<<dim3(256), 1024, 0, stream>>>(x, eps, Wf, bf, out);
}